// Round 4
// baseline (288.734 us; speedup 1.0000x reference)
//
#include <hip/hip_runtime.h>
#include <hip/hip_bf16.h>
#include <stdint.h>

#define B 4
#define N 2048
#define DIN 128
#define H 4
#define HD 32
#define NEG 0.2f

// ================= FAST PATH (needs ws >= 4.75 MB) =================

// ---------- Kernel A: h = x @ W^T  (8192x128x128 GEMM) ----------
__global__ __launch_bounds__(256) void k_gemm(const float* __restrict__ x,
                                              const float* __restrict__ W,
                                              float* __restrict__ h) {
    __shared__ float Wt[64][128];   // [kk][c]
    __shared__ float xT[64][36];    // [kk][r], padded
    const int tid = threadIdx.x;
    const int r0 = (tid >> 6) * 8;
    const int c2 = tid & 63;
    const int rowBase = blockIdx.x * 32;
    float acc[8][2];
#pragma unroll
    for (int i = 0; i < 8; ++i) { acc[i][0] = 0.f; acc[i][1] = 0.f; }

    for (int kh = 0; kh < 2; ++kh) {
        __syncthreads();
        {   // Wt[kk][c] = W[c][kh*64+kk]
            const int c = tid & 127;
            const int qb = (tid >> 7) * 8;
            const float4* W4 = (const float4*)W;
#pragma unroll
            for (int q = 0; q < 8; ++q) {
                float4 v = W4[c * 32 + kh * 16 + qb + q];
                int kk = (qb + q) * 4;
                Wt[kk + 0][c] = v.x; Wt[kk + 1][c] = v.y;
                Wt[kk + 2][c] = v.z; Wt[kk + 3][c] = v.w;
            }
        }
        {   // xT[kk][r] = x[rowBase+r][kh*64+kk]
            const int rl = tid & 31;
            const int q0 = (tid >> 5) * 2;
            const float4* x4 = (const float4*)x;
#pragma unroll
            for (int qi = 0; qi < 2; ++qi) {
                int q = q0 + qi;
                float4 v = x4[(rowBase + rl) * 32 + kh * 16 + q];
                int kk = q * 4;
                xT[kk + 0][rl] = v.x; xT[kk + 1][rl] = v.y;
                xT[kk + 2][rl] = v.z; xT[kk + 3][rl] = v.w;
            }
        }
        __syncthreads();
#pragma unroll 8
        for (int kk = 0; kk < 64; ++kk) {
            float w0 = Wt[kk][c2 * 2 + 0];
            float w1 = Wt[kk][c2 * 2 + 1];
#pragma unroll
            for (int i = 0; i < 8; ++i) {
                float xv = xT[kk][r0 + i];
                acc[i][0] += xv * w0;
                acc[i][1] += xv * w1;
            }
        }
    }
#pragma unroll
    for (int i = 0; i < 8; ++i) {
        int gr = rowBase + r0 + i;
        *(float2*)&h[gr * 128 + c2 * 2] = make_float2(acc[i][0], acc[i][1]);
    }
}

// ---------- Kernel B1: ei/ej = per-head dot(h, a1/a2) ----------
__global__ __launch_bounds__(128) void k_eij(const float* __restrict__ h,
                                             const float* __restrict__ a,
                                             float* __restrict__ ei,
                                             float* __restrict__ ej) {
    const int gr = blockIdx.x;
    const int tid = threadIdx.x;
    const int head = tid >> 5, d = tid & 31;
    float hv = h[gr * 128 + tid];
    float v1 = hv * a[head * 64 + d];
    float v2 = hv * a[head * 64 + 32 + d];
#pragma unroll
    for (int off = 16; off > 0; off >>= 1) {
        v1 += __shfl_xor(v1, off);
        v2 += __shfl_xor(v2, off);
    }
    if (d == 0) {
        ei[gr * 4 + head] = v1;
        ej[gr * 4 + head] = v2;
    }
}

// ---------- Kernel B2: pack adjacency into bitmask ----------
__global__ __launch_bounds__(256) void k_pack(const int* __restrict__ adj,
                                              unsigned long long* __restrict__ bits) {
    int t = blockIdx.x * 256 + threadIdx.x;
    int v = adj[t];
    unsigned long long m = __ballot(v != 0);
    if ((threadIdx.x & 63) == 0) bits[t >> 6] = m;
}

// ---------- Kernel C: fused masked softmax (max-free) + PV, direct f32 out ----------
// 256 blocks = (b, head, 16 tiles of 128 rows); thread: 2 rows x 8 dims.
__global__ __launch_bounds__(256) void k_attn3(const float* __restrict__ h,
                                               const float* __restrict__ ei,
                                               const float* __restrict__ ej,
                                               const unsigned long long* __restrict__ bits,
                                               float* __restrict__ out) {
    __shared__ float h_s[64][32];
    __shared__ float ej_s[64];
    const int tid = threadIdx.x;
    const int bid = blockIdx.x;
    const int rt = bid & 15;
    const int head = (bid >> 4) & 3;
    const int b = bid >> 6;

    const int dgrp = tid & 3, d0 = dgrp * 8;
    const int rseg = tid >> 2;                 // 0..63
    const int rowL0 = rt * 128 + rseg * 2;     // node index of first row of pair
    const int grBase = b * N + rowL0;

    float eir[2];
    eir[0] = ei[(grBase + 0) * 4 + head];
    eir[1] = ei[(grBase + 1) * 4 + head];

    float acc[2][8];
    float sacc[2] = {0.f, 0.f};
#pragma unroll
    for (int k = 0; k < 2; ++k)
#pragma unroll
        for (int d = 0; d < 8; ++d) acc[k][d] = 0.f;

    for (int jc = 0; jc < N; jc += 64) {
        __syncthreads();
        {   // h_s[jj][d] = h[b, jc+jj, head, d]
            int jl = tid >> 2, dp = (tid & 3) * 8;
            const float4* src = (const float4*)&h[((b * N + jc + jl) * 4 + head) * 32 + dp];
            float4 v0 = src[0], v1 = src[1];
            *(float4*)&h_s[jl][dp] = v0;
            *(float4*)&h_s[jl][dp + 4] = v1;
        }
        if (tid < 64) ej_s[tid] = ej[(b * N + jc + tid) * 4 + head];
        unsigned long long w0 = bits[(rowL0 + 0) * (N / 64) + (jc >> 6)];
        unsigned long long w1 = bits[(rowL0 + 1) * (N / 64) + (jc >> 6)];
        __syncthreads();
#pragma unroll 2
        for (int jj = 0; jj < 64; ++jj) {
            float ejv = ej_s[jj];
            float hv[8];
            *(float4*)&hv[0] = *(const float4*)&h_s[jj][d0];
            *(float4*)&hv[4] = *(const float4*)&h_s[jj][d0 + 4];
            {
                float s = eir[0] + ejv;
                float el = s > 0.f ? s : NEG * s;
                float p = ((w0 >> jj) & 1ull) ? __expf(el) : 0.f;
                sacc[0] += p;
#pragma unroll
                for (int d = 0; d < 8; ++d) acc[0][d] += p * hv[d];
            }
            {
                float s = eir[1] + ejv;
                float el = s > 0.f ? s : NEG * s;
                float p = ((w1 >> jj) & 1ull) ? __expf(el) : 0.f;
                sacc[1] += p;
#pragma unroll
                for (int d = 0; d < 8; ++d) acc[1][d] += p * hv[d];
            }
        }
    }
#pragma unroll
    for (int k = 0; k < 2; ++k) {
        float inv = 1.f / sacc[k];
        float4 o0, o1;
        o0.x = acc[k][0] * inv; o0.y = acc[k][1] * inv;
        o0.z = acc[k][2] * inv; o0.w = acc[k][3] * inv;
        o1.x = acc[k][4] * inv; o1.y = acc[k][5] * inv;
        o1.z = acc[k][6] * inv; o1.w = acc[k][7] * inv;
        float* dst = &out[(grBase + k) * 128 + head * 32 + d0];
        *(float4*)&dst[0] = o0;
        *(float4*)&dst[4] = o1;
    }
}

// ================= FALLBACK: ZERO-WORKSPACE FUSED KERNEL =================
__global__ __launch_bounds__(256) void k_fused(const float* __restrict__ x,
                                               const int* __restrict__ adj,
                                               const float* __restrict__ W,
                                               const float* __restrict__ a,
                                               float* __restrict__ out) {
    __shared__ float Ws[32][129];
    __shared__ float xs[64][132];
    __shared__ float hs[64][44];
    __shared__ float ejs[64];
    __shared__ float eis[128];
    __shared__ float a1s[32], a2s[32];
    __shared__ unsigned long long mb[128];

    const int tid = threadIdx.x;
    const int bid = blockIdx.x;
    const int rt = bid & 15;
    const int head = (bid >> 4) & 3;
    const int b = bid >> 6;
    const int row0 = rt * 128;

    for (int idx = tid; idx < 32 * 128; idx += 256) {
        int d = idx >> 7, k = idx & 127;
        Ws[d][k] = W[(head * 32 + d) * 128 + k];
    }
    if (tid < 32) a1s[tid] = a[head * 64 + tid];
    else if (tid < 64) a2s[tid - 32] = a[head * 64 + tid];
    __syncthreads();

    for (int c0 = 0; c0 < 128; c0 += 64) {
        __syncthreads();
        {
            int jj = tid >> 2, k0 = (tid & 3) * 32;
            const float4* src = (const float4*)&x[(b * N + row0 + c0 + jj) * 128 + k0];
#pragma unroll
            for (int q = 0; q < 8; ++q) *(float4*)&xs[jj][k0 + q * 4] = src[q];
        }
        __syncthreads();
        {
            int jj = tid >> 2, db = (tid & 3) * 8;
#pragma unroll
            for (int dd = 0; dd < 8; ++dd) {
                float s = 0.f;
                for (int k = 0; k < 128; ++k) s += xs[jj][k] * Ws[db + dd][k];
                hs[jj][db + dd] = s;
            }
        }
        __syncthreads();
        if (tid < 64) {
            float s = 0.f;
#pragma unroll
            for (int d = 0; d < 32; ++d) s += hs[tid][d] * a1s[d];
            eis[c0 + tid] = s;
        }
    }

    const int dgrp = tid & 3, d0 = dgrp * 8;
    const int rseg = tid >> 2;
    float acc[2][8];
    float sacc[2] = {0.f, 0.f};
#pragma unroll
    for (int k = 0; k < 2; ++k)
#pragma unroll
        for (int d = 0; d < 8; ++d) acc[k][d] = 0.f;

    for (int jc = 0; jc < N; jc += 64) {
        __syncthreads();
        {
            int jj = tid >> 2, k0 = (tid & 3) * 32;
            const float4* src = (const float4*)&x[(b * N + jc + jj) * 128 + k0];
#pragma unroll
            for (int q = 0; q < 8; ++q) *(float4*)&xs[jj][k0 + q * 4] = src[q];
        }
        {
            int wv = tid >> 6, lane = tid & 63;
            for (int p = 0; p < 32; ++p) {
                int il = p * 4 + wv;
                unsigned long long m = __ballot(adj[(row0 + il) * N + jc + lane] != 0);
                if (lane == 0) mb[il] = m;
            }
        }
        __syncthreads();
        {
            int jj = tid >> 2, db = (tid & 3) * 8;
#pragma unroll
            for (int dd = 0; dd < 8; ++dd) {
                float s = 0.f;
                for (int k = 0; k < 128; ++k) s += xs[jj][k] * Ws[db + dd][k];
                hs[jj][db + dd] = s;
            }
        }
        __syncthreads();
        if (tid < 64) {
            float s = 0.f;
#pragma unroll
            for (int d = 0; d < 32; ++d) s += hs[tid][d] * a2s[d];
            ejs[tid] = s;
        }
        __syncthreads();
        for (int jj = 0; jj < 64; ++jj) {
            float ejv = ejs[jj];
            float hv[8];
#pragma unroll
            for (int d = 0; d < 8; ++d) hv[d] = hs[jj][d0 + d];
#pragma unroll
            for (int k = 0; k < 2; ++k) {
                int il = rseg * 2 + k;
                float s = eis[il] + ejv;
                float el = s > 0.f ? s : NEG * s;
                float p = ((mb[il] >> jj) & 1ull) ? __expf(el) : 0.f;
                sacc[k] += p;
#pragma unroll
                for (int d = 0; d < 8; ++d) acc[k][d] += p * hv[d];
            }
        }
    }
#pragma unroll
    for (int k = 0; k < 2; ++k) {
        int il = rseg * 2 + k;
        float inv = 1.f / sacc[k];
        float* dst = &out[(b * N + row0 + il) * 128 + head * 32 + d0];
#pragma unroll
        for (int d = 0; d < 8; ++d) dst[d] = acc[k][d] * inv;
    }
}

extern "C" void kernel_launch(void* const* d_in, const int* in_sizes, int n_in,
                              void* d_out, int out_size, void* d_ws, size_t ws_size,
                              hipStream_t stream) {
    // Identify inputs by element count (all unique) — order-proof.
    const float* x = nullptr; const int* adj = nullptr;
    const float* W = nullptr; const float* a = nullptr;
    for (int i = 0; i < n_in; ++i) {
        switch (in_sizes[i]) {
            case B * N * DIN:  x   = (const float*)d_in[i]; break;  // 1048576
            case N * N:        adj = (const int*)d_in[i];   break;  // 4194304
            case H * HD * DIN: W   = (const float*)d_in[i]; break;  // 16384
            case H * 2 * HD:   a   = (const float*)d_in[i]; break;  // 256
        }
    }
    float* out = (float*)d_out;   // reference output dtype is float32

    const size_t need = (size_t)(B * N) * DIN * 4          // h: 4 MB
                      + (size_t)(B * N) * H * 4 * 2        // ei+ej: 256 KB
                      + (size_t)N * (N / 64) * 8;          // bits: 512 KB

    if (ws_size >= need) {
        char* ws = (char*)d_ws;
        float* h  = (float*)(ws);
        float* ei = (float*)(ws + (size_t)(B * N) * DIN * 4);
        float* ej = ei + (size_t)(B * N) * H;
        unsigned long long* bits = (unsigned long long*)(ej + (size_t)(B * N) * H);

        k_gemm<<<256, 256, 0, stream>>>(x, W, h);
        k_eij<<<B * N, 128, 0, stream>>>(h, a, ei, ej);
        k_pack<<<(N * N) / 256, 256, 0, stream>>>(adj, bits);
        k_attn3<<<256, 256, 0, stream>>>(h, ei, ej, bits, out);
    } else {
        k_fused<<<256, 256, 0, stream>>>(x, adj, W, a, out);
    }
}

// Round 5
// 149.002 us; speedup vs baseline: 1.9378x; 1.9378x over previous
//
#include <hip/hip_runtime.h>
#include <hip/hip_bf16.h>
#include <stdint.h>

#define B 4
#define N 2048
#define DIN 128
#define H 4
#define HD 32
#define NEG 0.2f

typedef __attribute__((ext_vector_type(8))) short short8;
typedef __attribute__((ext_vector_type(4))) float f32x4;

// ---------- Kernel A: h = x @ W^T  (8192x128x128 GEMM) ----------
__global__ __launch_bounds__(256) void k_gemm(const float* __restrict__ x,
                                              const float* __restrict__ W,
                                              float* __restrict__ h) {
    __shared__ float Wt[64][128];   // [kk][c]
    __shared__ float xT[64][36];    // [kk][r], padded
    const int tid = threadIdx.x;
    const int r0 = (tid >> 6) * 8;
    const int c2 = tid & 63;
    const int rowBase = blockIdx.x * 32;
    float acc[8][2];
#pragma unroll
    for (int i = 0; i < 8; ++i) { acc[i][0] = 0.f; acc[i][1] = 0.f; }

    for (int kh = 0; kh < 2; ++kh) {
        __syncthreads();
        {   // Wt[kk][c] = W[c][kh*64+kk]
            const int c = tid & 127;
            const int qb = (tid >> 7) * 8;
            const float4* W4 = (const float4*)W;
#pragma unroll
            for (int q = 0; q < 8; ++q) {
                float4 v = W4[c * 32 + kh * 16 + qb + q];
                int kk = (qb + q) * 4;
                Wt[kk + 0][c] = v.x; Wt[kk + 1][c] = v.y;
                Wt[kk + 2][c] = v.z; Wt[kk + 3][c] = v.w;
            }
        }
        {   // xT[kk][r] = x[rowBase+r][kh*64+kk]
            const int rl = tid & 31;
            const int q0 = (tid >> 5) * 2;
            const float4* x4 = (const float4*)x;
#pragma unroll
            for (int qi = 0; qi < 2; ++qi) {
                int q = q0 + qi;
                float4 v = x4[(rowBase + rl) * 32 + kh * 16 + q];
                int kk = q * 4;
                xT[kk + 0][rl] = v.x; xT[kk + 1][rl] = v.y;
                xT[kk + 2][rl] = v.z; xT[kk + 3][rl] = v.w;
            }
        }
        __syncthreads();
#pragma unroll 8
        for (int kk = 0; kk < 64; ++kk) {
            float w0 = Wt[kk][c2 * 2 + 0];
            float w1 = Wt[kk][c2 * 2 + 1];
#pragma unroll
            for (int i = 0; i < 8; ++i) {
                float xv = xT[kk][r0 + i];
                acc[i][0] += xv * w0;
                acc[i][1] += xv * w1;
            }
        }
    }
#pragma unroll
    for (int i = 0; i < 8; ++i) {
        int gr = rowBase + r0 + i;
        *(float2*)&h[gr * 128 + c2 * 2] = make_float2(acc[i][0], acc[i][1]);
    }
}

// ---------- Kernel B1: ei/ej = per-head dot(h, a1/a2) ----------
__global__ __launch_bounds__(128) void k_eij(const float* __restrict__ h,
                                             const float* __restrict__ a,
                                             float* __restrict__ ei,
                                             float* __restrict__ ej) {
    const int gr = blockIdx.x;
    const int tid = threadIdx.x;
    const int head = tid >> 5, d = tid & 31;
    float hv = h[gr * 128 + tid];
    float v1 = hv * a[head * 64 + d];
    float v2 = hv * a[head * 64 + 32 + d];
#pragma unroll
    for (int off = 16; off > 0; off >>= 1) {
        v1 += __shfl_xor(v1, off);
        v2 += __shfl_xor(v2, off);
    }
    if (d == 0) {
        ei[gr * 4 + head] = v1;
        ej[gr * 4 + head] = v2;
    }
}

// ---------- Kernel B2: pack adjacency into bitmask ----------
__global__ __launch_bounds__(256) void k_pack(const int* __restrict__ adj,
                                              unsigned long long* __restrict__ bits) {
    int t = blockIdx.x * 256 + threadIdx.x;
    int v = adj[t];
    unsigned long long m = __ballot(v != 0);
    if ((threadIdx.x & 63) == 0) bits[t >> 6] = m;
}

// ---------- Kernel C (MFMA): masked max-free softmax + PV via mfma 16x16x32 ----------
// grid 512 = b(4) x head(4) x rowtile(32 of 64 rows); block = 4 waves, wave = 16 rows.
// A-frag: lane holds p[row = lane&15][j = jbase + 8*(lane>>4) + e]  (e=0..7)
// B-frag: lane holds V^T[d = lane&15 (+16)][same j slice] from LDS, ds_read_b128.
// Any k-relabeling cancels because A and B use the identical (g,e)->j map.
// C/D (HW-verified): col = lane&15 (d), row = 4*(lane>>4)+reg.
__global__ __launch_bounds__(256) void k_attn_m(const float* __restrict__ h,
                                                const float* __restrict__ ei,
                                                const float* __restrict__ ej,
                                                const unsigned long long* __restrict__ bits,
                                                float* __restrict__ out) {
    __shared__ __align__(16) unsigned short VT[32][72];  // bf16 V^T, padded: 144B rows
    __shared__ float ej_s[64];

    const int tid = threadIdx.x;
    const int bid = blockIdx.x;
    const int rt = bid & 31;
    const int head = (bid >> 5) & 3;
    const int b = bid >> 7;
    const int wv = tid >> 6, lane = tid & 63;
    const int lr = lane & 15;       // A-row within tile / output d-col
    const int g = lane >> 4;        // k lane-group
    const int rowW = rt * 64 + wv * 16;     // wave's first row (node idx)

    const float eir = ei[(b * N + rowW + lr) * 4 + head];
    const unsigned long long* browp = &bits[(size_t)(rowW + lr) * (N / 64)];

    f32x4 acc0 = {0.f, 0.f, 0.f, 0.f};
    f32x4 acc1 = {0.f, 0.f, 0.f, 0.f};
    float sacc = 0.f;

    for (int jc = 0; jc < N; jc += 64) {
        __syncthreads();
        {   // stage V^T (bf16) + ej chunk
            const int jj = tid >> 2, dgrp = tid & 3;
            const float4* src =
                (const float4*)&h[((size_t)(b * N + jc + jj) * 4 + head) * 32 + dgrp * 8];
            float4 v0 = src[0], v1 = src[1];
            float vv[8] = {v0.x, v0.y, v0.z, v0.w, v1.x, v1.y, v1.z, v1.w};
#pragma unroll
            for (int q = 0; q < 8; ++q) {
                __hip_bfloat16 hb = __float2bfloat16(vv[q]);
                VT[dgrp * 8 + q][jj] = *(unsigned short*)&hb;
            }
        }
        if (tid < 64) ej_s[tid] = ej[(b * N + jc + tid) * 4 + head];
        __syncthreads();

        const unsigned long long wrow = browp[jc >> 6];
#pragma unroll
        for (int ks = 0; ks < 2; ++ks) {
            const int joff = ks * 32 + g * 8;
            const unsigned int mbyte = (unsigned int)(wrow >> joff) & 0xffu;
            float4 ea = *(const float4*)&ej_s[joff];
            float4 eb = *(const float4*)&ej_s[joff + 4];
            float ejv[8] = {ea.x, ea.y, ea.z, ea.w, eb.x, eb.y, eb.z, eb.w};
            short8 pa;
#pragma unroll
            for (int e = 0; e < 8; ++e) {
                float s = eir + ejv[e];
                float el = s > 0.f ? s : NEG * s;
                float p = ((mbyte >> e) & 1u) ? __expf(el) : 0.f;
                __hip_bfloat16 pb = __float2bfloat16(p);
                unsigned short u = *(unsigned short*)&pb;
                pa[e] = (short)u;
                sacc += __uint_as_float((unsigned int)u << 16);  // rounded p -> no norm bias
            }
            short8 b0 = *(const short8*)&VT[lr][joff];
            short8 b1 = *(const short8*)&VT[16 + lr][joff];
            acc0 = __builtin_amdgcn_mfma_f32_16x16x32_bf16(pa, b0, acc0, 0, 0, 0);
            acc1 = __builtin_amdgcn_mfma_f32_16x16x32_bf16(pa, b1, acc1, 0, 0, 0);
        }
    }

    // full row-sum: combine the 4 k-groups (lanes sharing lr)
    sacc += __shfl_xor(sacc, 16);
    sacc += __shfl_xor(sacc, 32);

#pragma unroll
    for (int reg = 0; reg < 4; ++reg) {
        const int m = 4 * g + reg;                 // output row within tile
        const float sr = __shfl(sacc, (lane & 48) | m);
        const float inv = 1.f / sr;
        float* dst = &out[(size_t)(b * N + rowW + m) * 128 + head * 32 + lr];
        dst[0]  = acc0[reg] * inv;
        dst[16] = acc1[reg] * inv;
    }
}

// ================= FALLBACK: ZERO-WORKSPACE FUSED KERNEL =================
__global__ __launch_bounds__(256) void k_fused(const float* __restrict__ x,
                                               const int* __restrict__ adj,
                                               const float* __restrict__ W,
                                               const float* __restrict__ a,
                                               float* __restrict__ out) {
    __shared__ float Ws[32][129];
    __shared__ float xs[64][132];
    __shared__ float hs[64][44];
    __shared__ float ejs[64];
    __shared__ float eis[128];
    __shared__ float a1s[32], a2s[32];
    __shared__ unsigned long long mb[128];

    const int tid = threadIdx.x;
    const int bid = blockIdx.x;
    const int rt = bid & 15;
    const int head = (bid >> 4) & 3;
    const int b = bid >> 6;
    const int row0 = rt * 128;

    for (int idx = tid; idx < 32 * 128; idx += 256) {
        int d = idx >> 7, k = idx & 127;
        Ws[d][k] = W[(head * 32 + d) * 128 + k];
    }
    if (tid < 32) a1s[tid] = a[head * 64 + tid];
    else if (tid < 64) a2s[tid - 32] = a[head * 64 + tid];
    __syncthreads();

    for (int c0 = 0; c0 < 128; c0 += 64) {
        __syncthreads();
        {
            int jj = tid >> 2, k0 = (tid & 3) * 32;
            const float4* src = (const float4*)&x[(b * N + row0 + c0 + jj) * 128 + k0];
#pragma unroll
            for (int q = 0; q < 8; ++q) *(float4*)&xs[jj][k0 + q * 4] = src[q];
        }
        __syncthreads();
        {
            int jj = tid >> 2, db = (tid & 3) * 8;
#pragma unroll
            for (int dd = 0; dd < 8; ++dd) {
                float s = 0.f;
                for (int k = 0; k < 128; ++k) s += xs[jj][k] * Ws[db + dd][k];
                hs[jj][db + dd] = s;
            }
        }
        __syncthreads();
        if (tid < 64) {
            float s = 0.f;
#pragma unroll
            for (int d = 0; d < 32; ++d) s += hs[tid][d] * a1s[d];
            eis[c0 + tid] = s;
        }
    }

    const int dgrp = tid & 3, d0 = dgrp * 8;
    const int rseg = tid >> 2;
    float acc[2][8];
    float sacc[2] = {0.f, 0.f};
#pragma unroll
    for (int k = 0; k < 2; ++k)
#pragma unroll
        for (int d = 0; d < 8; ++d) acc[k][d] = 0.f;

    for (int jc = 0; jc < N; jc += 64) {
        __syncthreads();
        {
            int jj = tid >> 2, k0 = (tid & 3) * 32;
            const float4* src = (const float4*)&x[(b * N + jc + jj) * 128 + k0];
#pragma unroll
            for (int q = 0; q < 8; ++q) *(float4*)&xs[jj][k0 + q * 4] = src[q];
        }
        {
            int wv = tid >> 6, lane = tid & 63;
            for (int p = 0; p < 32; ++p) {
                int il = p * 4 + wv;
                unsigned long long m = __ballot(adj[(row0 + il) * N + jc + lane] != 0);
                if (lane == 0) mb[il] = m;
            }
        }
        __syncthreads();
        {
            int jj = tid >> 2, db = (tid & 3) * 8;
#pragma unroll
            for (int dd = 0; dd < 8; ++dd) {
                float s = 0.f;
                for (int k = 0; k < 128; ++k) s += xs[jj][k] * Ws[db + dd][k];
                hs[jj][db + dd] = s;
            }
        }
        __syncthreads();
        if (tid < 64) {
            float s = 0.f;
#pragma unroll
            for (int d = 0; d < 32; ++d) s += hs[tid][d] * a2s[d];
            ejs[tid] = s;
        }
        __syncthreads();
        for (int jj = 0; jj < 64; ++jj) {
            float ejv = ejs[jj];
            float hv[8];
#pragma unroll
            for (int d = 0; d < 8; ++d) hv[d] = hs[jj][d0 + d];
#pragma unroll
            for (int k = 0; k < 2; ++k) {
                int il = rseg * 2 + k;
                float s = eis[il] + ejv;
                float el = s > 0.f ? s : NEG * s;
                float p = ((mb[il] >> jj) & 1ull) ? __expf(el) : 0.f;
                sacc[k] += p;
#pragma unroll
                for (int d = 0; d < 8; ++d) acc[k][d] += p * hv[d];
            }
        }
    }
#pragma unroll
    for (int k = 0; k < 2; ++k) {
        int il = rseg * 2 + k;
        float inv = 1.f / sacc[k];
        float* dst = &out[(b * N + row0 + il) * 128 + head * 32 + d0];
#pragma unroll
        for (int d = 0; d < 8; ++d) dst[d] = acc[k][d] * inv;
    }
}

extern "C" void kernel_launch(void* const* d_in, const int* in_sizes, int n_in,
                              void* d_out, int out_size, void* d_ws, size_t ws_size,
                              hipStream_t stream) {
    // Identify inputs by element count (all unique) — order-proof.
    const float* x = nullptr; const int* adj = nullptr;
    const float* W = nullptr; const float* a = nullptr;
    for (int i = 0; i < n_in; ++i) {
        switch (in_sizes[i]) {
            case B * N * DIN:  x   = (const float*)d_in[i]; break;  // 1048576
            case N * N:        adj = (const int*)d_in[i];   break;  // 4194304
            case H * HD * DIN: W   = (const float*)d_in[i]; break;  // 16384
            case H * 2 * HD:   a   = (const float*)d_in[i]; break;  // 256
        }
    }
    float* out = (float*)d_out;   // reference output dtype is float32

    const size_t need = (size_t)(B * N) * DIN * 4          // h: 4 MB
                      + (size_t)(B * N) * H * 4 * 2        // ei+ej: 256 KB
                      + (size_t)N * (N / 64) * 8;          // bits: 512 KB

    if (ws_size >= need) {
        char* ws = (char*)d_ws;
        float* h  = (float*)(ws);
        float* ei = (float*)(ws + (size_t)(B * N) * DIN * 4);
        float* ej = ei + (size_t)(B * N) * H;
        unsigned long long* bits = (unsigned long long*)(ej + (size_t)(B * N) * H);

        k_gemm<<<256, 256, 0, stream>>>(x, W, h);
        k_eij<<<B * N, 128, 0, stream>>>(h, a, ei, ej);
        k_pack<<<(N * N) / 256, 256, 0, stream>>>(adj, bits);
        k_attn_m<<<512, 256, 0, stream>>>(h, ei, ej, bits, out);
    } else {
        k_fused<<<256, 256, 0, stream>>>(x, adj, W, a, out);
    }
}

// Round 6
// 130.453 us; speedup vs baseline: 2.2133x; 1.1422x over previous
//
#include <hip/hip_runtime.h>
#include <hip/hip_bf16.h>
#include <stdint.h>

#define B 4
#define N 2048
#define DIN 128
#define H 4
#define HD 32
#define NEG 0.2f

typedef __attribute__((ext_vector_type(8))) short short8;
typedef __attribute__((ext_vector_type(4))) float f32x4;

// ---------- Kernel A: h = x@W^T fused: writes V^T bf16 [bh][d][n] + ei/ej ----------
// grid 512 (16 rows each) x 256 thr; thread: 4 rows x 2 cols.
__global__ __launch_bounds__(256) void k_gemm(const float* __restrict__ x,
                                              const float* __restrict__ W,
                                              const float* __restrict__ a,
                                              unsigned short* __restrict__ VT,
                                              float* __restrict__ ei_t,
                                              float* __restrict__ ej_t) {
    __shared__ float Wt0[64][64];   // even cols  [kk][c>>1]
    __shared__ float Wt1[64][64];   // odd cols
    __shared__ float xT[64][20];    // [kk][r], padded
    const int tid = threadIdx.x;
    const int lane = tid & 63;
    const int r0 = (tid >> 6) * 4;        // wave -> 4 rows
    const int c2 = lane;                  // cols 2*c2, 2*c2+1
    const int rowBase = blockIdx.x * 16;
    float acc[4][2];
#pragma unroll
    for (int i = 0; i < 4; ++i) { acc[i][0] = 0.f; acc[i][1] = 0.f; }

    for (int kh = 0; kh < 2; ++kh) {
        __syncthreads();
        {   // stage W half, split even/odd col planes (conflict-free)
            const int c = tid & 127;
            const int qb = (tid >> 7) * 8;
            const int ci = c >> 1, pl = c & 1;
            const float4* W4 = (const float4*)W;
#pragma unroll
            for (int q = 0; q < 8; ++q) {
                float4 v = W4[c * 32 + kh * 16 + qb + q];
                int kk = (qb + q) * 4;
                if (pl == 0) {
                    Wt0[kk + 0][ci] = v.x; Wt0[kk + 1][ci] = v.y;
                    Wt0[kk + 2][ci] = v.z; Wt0[kk + 3][ci] = v.w;
                } else {
                    Wt1[kk + 0][ci] = v.x; Wt1[kk + 1][ci] = v.y;
                    Wt1[kk + 2][ci] = v.z; Wt1[kk + 3][ci] = v.w;
                }
            }
        }
        {   // stage x: xT[kk][r] = x[rowBase+r][kh*64+kk]; 256 thr = 16 rows x 16 f4
            const int rl = tid >> 4;
            const int q = tid & 15;
            float4 v = ((const float4*)x)[(rowBase + rl) * 32 + kh * 16 + q];
            int kk = q * 4;
            xT[kk + 0][rl] = v.x; xT[kk + 1][rl] = v.y;
            xT[kk + 2][rl] = v.z; xT[kk + 3][rl] = v.w;
        }
        __syncthreads();
#pragma unroll 8
        for (int kk = 0; kk < 64; ++kk) {
            float w0 = Wt0[kk][c2];
            float w1 = Wt1[kk][c2];
#pragma unroll
            for (int i = 0; i < 4; ++i) {
                float xv = xT[kk][r0 + i];
                acc[i][0] += xv * w0;
                acc[i][1] += xv * w1;
            }
        }
    }

    // ---- epilogue: V^T bf16 store + inline ei/ej ----
    const int c0 = 2 * c2;
    const int head = c0 >> 5, d0 = c0 & 31;
    const int b = rowBase >> 11;
    const int n0 = (rowBase & 2047) + r0;
    const int bh = b * 4 + head;

    {   // pack 4 consecutive n per col -> ushort4
        ushort4 p0, p1;
        unsigned short* q0 = (unsigned short*)&p0;
        unsigned short* q1 = (unsigned short*)&p1;
#pragma unroll
        for (int i = 0; i < 4; ++i) {
            __hip_bfloat16 h0 = __float2bfloat16(acc[i][0]);
            __hip_bfloat16 h1 = __float2bfloat16(acc[i][1]);
            q0[i] = *(unsigned short*)&h0;
            q1[i] = *(unsigned short*)&h1;
        }
        *(ushort4*)&VT[((size_t)bh * 32 + d0) * 2048 + n0] = p0;
        *(ushort4*)&VT[((size_t)bh * 32 + d0 + 1) * 2048 + n0] = p1;
    }
    {
        float a10 = a[head * 64 + d0],      a11 = a[head * 64 + d0 + 1];
        float a20 = a[head * 64 + 32 + d0], a21 = a[head * 64 + 32 + d0 + 1];
#pragma unroll
        for (int i = 0; i < 4; ++i) {
            float pi = acc[i][0] * a10 + acc[i][1] * a11;
            float pj = acc[i][0] * a20 + acc[i][1] * a21;
#pragma unroll
            for (int off = 1; off < 16; off <<= 1) {   // reduce 16-lane head group
                pi += __shfl_xor(pi, off);
                pj += __shfl_xor(pj, off);
            }
            if ((lane & 15) == 0) {
                ei_t[(size_t)bh * 2048 + n0 + i] = pi;
                ej_t[(size_t)bh * 2048 + n0 + i] = pj;
            }
        }
    }
}

// ---------- Kernel B2: pack adjacency into bitmask ----------
__global__ __launch_bounds__(256) void k_pack(const int* __restrict__ adj,
                                              unsigned long long* __restrict__ bits) {
    int t = blockIdx.x * 256 + threadIdx.x;
    int v = adj[t];
    unsigned long long m = __ballot(v != 0);
    if ((threadIdx.x & 63) == 0) bits[t >> 6] = m;
}

// ---------- Kernel C: barrier-free MFMA attention ----------
// grid 512 = b(4) x head(4) x rowtile(32 of 64 rows); block = 8 waves.
// waves 0-3: row-subtiles, even j-chunks; waves 4-7: same subtiles, odd chunks.
// lane: lr = lane&15 (P-row AND V-d-col), g = lane>>4 (k-slice).
// Row sums via third MFMA with ones-column B (rounded-p consistent).
__global__ __launch_bounds__(512) void k_attn_g(const unsigned short* __restrict__ VT,
                                                const float* __restrict__ ei_t,
                                                const float* __restrict__ ej_t,
                                                const unsigned long long* __restrict__ bits,
                                                float* __restrict__ out) {
    __shared__ float red[4][64][13];

    const int tid = threadIdx.x;
    const int bid = blockIdx.x;
    const int rt = bid & 31;
    const int head = (bid >> 5) & 3;
    const int b = bid >> 7;
    const int wv = tid >> 6, lane = tid & 63;
    const int wtile = wv & 3, par = wv >> 2;
    const int lr = lane & 15;
    const int g = lane >> 4;
    const int rowW = rt * 64 + wtile * 16;
    const int bh = b * 4 + head;

    const unsigned short* V0 = VT + (size_t)bh * 32 * 2048 + (size_t)lr * 2048;
    const unsigned short* V1 = V0 + 16 * 2048;
    const float* ejp = ej_t + (size_t)bh * 2048;
    const float eir = ei_t[(size_t)bh * 2048 + rowW + lr];
    const unsigned long long* mrow = bits + (size_t)(rowW + lr) * (N / 64);

    f32x4 acc0 = {0.f, 0.f, 0.f, 0.f};
    f32x4 acc1 = {0.f, 0.f, 0.f, 0.f};
    f32x4 accS = {0.f, 0.f, 0.f, 0.f};
    short8 onesb;
    {
        short ov = (lr == 0) ? (short)0x3F80 : (short)0;   // bf16 1.0 in col 0
#pragma unroll
        for (int e = 0; e < 8; ++e) onesb[e] = ov;
    }

    for (int jc = par * 64; jc < N; jc += 128) {
        const unsigned long long word = mrow[jc >> 6];
#pragma unroll
        for (int ks = 0; ks < 2; ++ks) {
            const int joff = jc + ks * 32 + g * 8;
            float4 ea = *(const float4*)(ejp + joff);
            float4 eb = *(const float4*)(ejp + joff + 4);
            short8 b0 = *(const short8*)(V0 + joff);
            short8 b1 = *(const short8*)(V1 + joff);
            const unsigned int mb = (unsigned int)(word >> (ks * 32 + g * 8)) & 0xffu;
            float ej8[8] = {ea.x, ea.y, ea.z, ea.w, eb.x, eb.y, eb.z, eb.w};
            short8 pa;
#pragma unroll
            for (int e = 0; e < 8; ++e) {
                float s = eir + ej8[e];
                float el = fmaxf(s, NEG * s);           // exact leaky-relu
                float p = ((mb >> e) & 1u) ? __expf(el) : 0.f;
                __hip_bfloat16 pb = __float2bfloat16(p);
                pa[e] = (short)*(unsigned short*)&pb;
            }
            acc0 = __builtin_amdgcn_mfma_f32_16x16x32_bf16(pa, b0, acc0, 0, 0, 0);
            acc1 = __builtin_amdgcn_mfma_f32_16x16x32_bf16(pa, b1, acc1, 0, 0, 0);
            accS = __builtin_amdgcn_mfma_f32_16x16x32_bf16(pa, onesb, accS, 0, 0, 0);
        }
    }

    // combine j-parity pairs through LDS
    if (par == 1) {
        float* r = &red[wtile][lane][0];
#pragma unroll
        for (int q = 0; q < 4; ++q) {
            r[q] = acc0[q]; r[4 + q] = acc1[q]; r[8 + q] = accS[q];
        }
    }
    __syncthreads();
    if (par == 0) {
        const float* r = &red[wtile][lane][0];
#pragma unroll
        for (int q = 0; q < 4; ++q) {
            acc0[q] += r[q]; acc1[q] += r[4 + q]; accS[q] += r[8 + q];
        }
        // C/D layout (HW-verified): col = lane&15, row = 4*(lane>>4)+reg.
        // rowsum of row m sits in lane (m>>2)*16 = g*16, reg = m&3.
#pragma unroll
        for (int reg = 0; reg < 4; ++reg) {
            const float sr = __shfl(accS[reg], g * 16);
            const float inv = 1.f / sr;
            const int m = 4 * g + reg;
            float* dst = &out[(size_t)(b * N + rowW + m) * 128 + head * 32 + lr];
            dst[0]  = acc0[reg] * inv;
            dst[16] = acc1[reg] * inv;
        }
    }
}

// ================= FALLBACK: ZERO-WORKSPACE FUSED KERNEL =================
__global__ __launch_bounds__(256) void k_fused(const float* __restrict__ x,
                                               const int* __restrict__ adj,
                                               const float* __restrict__ W,
                                               const float* __restrict__ a,
                                               float* __restrict__ out) {
    __shared__ float Ws[32][129];
    __shared__ float xs[64][132];
    __shared__ float hs[64][44];
    __shared__ float ejs[64];
    __shared__ float eis[128];
    __shared__ float a1s[32], a2s[32];
    __shared__ unsigned long long mb[128];

    const int tid = threadIdx.x;
    const int bid = blockIdx.x;
    const int rt = bid & 15;
    const int head = (bid >> 4) & 3;
    const int b = bid >> 6;
    const int row0 = rt * 128;

    for (int idx = tid; idx < 32 * 128; idx += 256) {
        int d = idx >> 7, k = idx & 127;
        Ws[d][k] = W[(head * 32 + d) * 128 + k];
    }
    if (tid < 32) a1s[tid] = a[head * 64 + tid];
    else if (tid < 64) a2s[tid - 32] = a[head * 64 + tid];
    __syncthreads();

    for (int c0 = 0; c0 < 128; c0 += 64) {
        __syncthreads();
        {
            int jj = tid >> 2, k0 = (tid & 3) * 32;
            const float4* src = (const float4*)&x[(b * N + row0 + c0 + jj) * 128 + k0];
#pragma unroll
            for (int q = 0; q < 8; ++q) *(float4*)&xs[jj][k0 + q * 4] = src[q];
        }
        __syncthreads();
        {
            int jj = tid >> 2, db = (tid & 3) * 8;
#pragma unroll
            for (int dd = 0; dd < 8; ++dd) {
                float s = 0.f;
                for (int k = 0; k < 128; ++k) s += xs[jj][k] * Ws[db + dd][k];
                hs[jj][db + dd] = s;
            }
        }
        __syncthreads();
        if (tid < 64) {
            float s = 0.f;
#pragma unroll
            for (int d = 0; d < 32; ++d) s += hs[tid][d] * a1s[d];
            eis[c0 + tid] = s;
        }
    }

    const int dgrp = tid & 3, d0 = dgrp * 8;
    const int rseg = tid >> 2;
    float acc[2][8];
    float sacc[2] = {0.f, 0.f};
#pragma unroll
    for (int k = 0; k < 2; ++k)
#pragma unroll
        for (int d = 0; d < 8; ++d) acc[k][d] = 0.f;

    for (int jc = 0; jc < N; jc += 64) {
        __syncthreads();
        {
            int jj = tid >> 2, k0 = (tid & 3) * 32;
            const float4* src = (const float4*)&x[(b * N + jc + jj) * 128 + k0];
#pragma unroll
            for (int q = 0; q < 8; ++q) *(float4*)&xs[jj][k0 + q * 4] = src[q];
        }
        {
            int wv = tid >> 6, lane = tid & 63;
            for (int p = 0; p < 32; ++p) {
                int il = p * 4 + wv;
                unsigned long long m = __ballot(adj[(row0 + il) * N + jc + lane] != 0);
                if (lane == 0) mb[il] = m;
            }
        }
        __syncthreads();
        {
            int jj = tid >> 2, db = (tid & 3) * 8;
#pragma unroll
            for (int dd = 0; dd < 8; ++dd) {
                float s = 0.f;
                for (int k = 0; k < 128; ++k) s += xs[jj][k] * Ws[db + dd][k];
                hs[jj][db + dd] = s;
            }
        }
        __syncthreads();
        if (tid < 64) {
            float s = 0.f;
#pragma unroll
            for (int d = 0; d < 32; ++d) s += hs[tid][d] * a2s[d];
            ejs[tid] = s;
        }
        __syncthreads();
        for (int jj = 0; jj < 64; ++jj) {
            float ejv = ejs[jj];
            float hv[8];
#pragma unroll
            for (int d = 0; d < 8; ++d) hv[d] = hs[jj][d0 + d];
#pragma unroll
            for (int k = 0; k < 2; ++k) {
                int il = rseg * 2 + k;
                float s = eis[il] + ejv;
                float el = s > 0.f ? s : NEG * s;
                float p = ((mb[il] >> jj) & 1ull) ? __expf(el) : 0.f;
                sacc[k] += p;
#pragma unroll
                for (int d = 0; d < 8; ++d) acc[k][d] += p * hv[d];
            }
        }
    }
#pragma unroll
    for (int k = 0; k < 2; ++k) {
        int il = rseg * 2 + k;
        float inv = 1.f / sacc[k];
        float* dst = &out[(b * N + row0 + il) * 128 + head * 32 + d0];
#pragma unroll
        for (int d = 0; d < 8; ++d) dst[d] = acc[k][d] * inv;
    }
}

extern "C" void kernel_launch(void* const* d_in, const int* in_sizes, int n_in,
                              void* d_out, int out_size, void* d_ws, size_t ws_size,
                              hipStream_t stream) {
    // Identify inputs by element count (all unique) — order-proof.
    const float* x = nullptr; const int* adj = nullptr;
    const float* W = nullptr; const float* a = nullptr;
    for (int i = 0; i < n_in; ++i) {
        switch (in_sizes[i]) {
            case B * N * DIN:  x   = (const float*)d_in[i]; break;  // 1048576
            case N * N:        adj = (const int*)d_in[i];   break;  // 4194304
            case H * HD * DIN: W   = (const float*)d_in[i]; break;  // 16384
            case H * 2 * HD:   a   = (const float*)d_in[i]; break;  // 256
        }
    }
    float* out = (float*)d_out;   // reference output dtype is float32

    // ws: VT bf16 2MB | ei_t 128KB | ej_t 128KB | bits 512KB  = 2.75 MB
    const size_t szVT = (size_t)B * H * HD * N * 2;
    const size_t szE  = (size_t)B * H * N * 4;
    const size_t szBits = (size_t)N * (N / 64) * 8;
    const size_t need = szVT + 2 * szE + szBits;

    if (ws_size >= need) {
        char* ws = (char*)d_ws;
        unsigned short* VT = (unsigned short*)ws;
        float* ei_t = (float*)(ws + szVT);
        float* ej_t = (float*)(ws + szVT + szE);
        unsigned long long* bits = (unsigned long long*)(ws + szVT + 2 * szE);

        k_gemm<<<512, 256, 0, stream>>>(x, W, a, VT, ei_t, ej_t);
        k_pack<<<(N * N) / 256, 256, 0, stream>>>(adj, bits);
        k_attn_g<<<512, 512, 0, stream>>>(VT, ei_t, ej_t, bits, out);
    } else {
        k_fused<<<256, 256, 0, stream>>>(x, adj, W, a, out);
    }
}

// Round 8
// 130.123 us; speedup vs baseline: 2.2189x; 1.0025x over previous
//
#include <hip/hip_runtime.h>
#include <hip/hip_bf16.h>
#include <stdint.h>

#define B 4
#define N 2048
#define DIN 128
#define H 4
#define HD 32
#define NEG 0.2f
#define LOG2E 1.4426950408889634f

typedef __attribute__((ext_vector_type(8))) short short8;
typedef __attribute__((ext_vector_type(4))) float f32x4;

// ---------- Kernel A: h = x@W^T fused: writes V^T bf16 [bh][d][n] + ei/ej ----------
// ei/ej are pre-scaled by log2(e) so attention can use raw v_exp_f32 (exp2).
// grid 512 (16 rows each) x 256 thr; thread: 4 rows x 2 cols.
__global__ __launch_bounds__(256) void k_gemm(const float* __restrict__ x,
                                              const float* __restrict__ W,
                                              const float* __restrict__ a,
                                              unsigned short* __restrict__ VT,
                                              float* __restrict__ ei_t,
                                              float* __restrict__ ej_t) {
    __shared__ float Wt0[64][64];   // even cols  [kk][c>>1]
    __shared__ float Wt1[64][64];   // odd cols
    __shared__ float xT[64][20];    // [kk][r], padded
    const int tid = threadIdx.x;
    const int lane = tid & 63;
    const int r0 = (tid >> 6) * 4;        // wave -> 4 rows
    const int c2 = lane;                  // cols 2*c2, 2*c2+1
    const int rowBase = blockIdx.x * 16;
    float acc[4][2];
#pragma unroll
    for (int i = 0; i < 4; ++i) { acc[i][0] = 0.f; acc[i][1] = 0.f; }

    for (int kh = 0; kh < 2; ++kh) {
        __syncthreads();
        {   // stage W half, split even/odd col planes (conflict-free)
            const int c = tid & 127;
            const int qb = (tid >> 7) * 8;
            const int ci = c >> 1, pl = c & 1;
            const float4* W4 = (const float4*)W;
#pragma unroll
            for (int q = 0; q < 8; ++q) {
                float4 v = W4[c * 32 + kh * 16 + qb + q];
                int kk = (qb + q) * 4;
                if (pl == 0) {
                    Wt0[kk + 0][ci] = v.x; Wt0[kk + 1][ci] = v.y;
                    Wt0[kk + 2][ci] = v.z; Wt0[kk + 3][ci] = v.w;
                } else {
                    Wt1[kk + 0][ci] = v.x; Wt1[kk + 1][ci] = v.y;
                    Wt1[kk + 2][ci] = v.z; Wt1[kk + 3][ci] = v.w;
                }
            }
        }
        {   // stage x: xT[kk][r] = x[rowBase+r][kh*64+kk]; 256 thr = 16 rows x 16 f4
            const int rl = tid >> 4;
            const int q = tid & 15;
            float4 v = ((const float4*)x)[(rowBase + rl) * 32 + kh * 16 + q];
            int kk = q * 4;
            xT[kk + 0][rl] = v.x; xT[kk + 1][rl] = v.y;
            xT[kk + 2][rl] = v.z; xT[kk + 3][rl] = v.w;
        }
        __syncthreads();
#pragma unroll 8
        for (int kk = 0; kk < 64; ++kk) {
            float w0 = Wt0[kk][c2];
            float w1 = Wt1[kk][c2];
#pragma unroll
            for (int i = 0; i < 4; ++i) {
                float xv = xT[kk][r0 + i];
                acc[i][0] += xv * w0;
                acc[i][1] += xv * w1;
            }
        }
    }

    // ---- epilogue: V^T bf16 store + inline ei/ej (log2e-scaled) ----
    const int c0 = 2 * c2;
    const int head = c0 >> 5, d0 = c0 & 31;
    const int b = rowBase >> 11;
    const int n0 = (rowBase & 2047) + r0;
    const int bh = b * 4 + head;

    {   // pack 4 consecutive n per col -> ushort4
        ushort4 p0, p1;
        unsigned short* q0 = (unsigned short*)&p0;
        unsigned short* q1 = (unsigned short*)&p1;
#pragma unroll
        for (int i = 0; i < 4; ++i) {
            __hip_bfloat16 h0 = __float2bfloat16(acc[i][0]);
            __hip_bfloat16 h1 = __float2bfloat16(acc[i][1]);
            q0[i] = *(unsigned short*)&h0;
            q1[i] = *(unsigned short*)&h1;
        }
        *(ushort4*)&VT[((size_t)bh * 32 + d0) * 2048 + n0] = p0;
        *(ushort4*)&VT[((size_t)bh * 32 + d0 + 1) * 2048 + n0] = p1;
    }
    {
        float a10 = a[head * 64 + d0],      a11 = a[head * 64 + d0 + 1];
        float a20 = a[head * 64 + 32 + d0], a21 = a[head * 64 + 32 + d0 + 1];
#pragma unroll
        for (int i = 0; i < 4; ++i) {
            float pi = acc[i][0] * a10 + acc[i][1] * a11;
            float pj = acc[i][0] * a20 + acc[i][1] * a21;
#pragma unroll
            for (int off = 1; off < 16; off <<= 1) {   // reduce 16-lane head group
                pi += __shfl_xor(pi, off);
                pj += __shfl_xor(pj, off);
            }
            if ((lane & 15) == 0) {
                ei_t[(size_t)bh * 2048 + n0 + i] = pi * LOG2E;
                ej_t[(size_t)bh * 2048 + n0 + i] = pj * LOG2E;
            }
        }
    }
}

// ---------- Kernel B2: pack adjacency into bitmask ----------
__global__ __launch_bounds__(256) void k_pack(const int* __restrict__ adj,
                                              unsigned long long* __restrict__ bits) {
    int t = blockIdx.x * 256 + threadIdx.x;
    int v = adj[t];
    unsigned long long m = __ballot(v != 0);
    if ((threadIdx.x & 63) == 0) bits[t >> 6] = m;
}

// ---------- Kernel C: barrier-free MFMA attention, pipelined ----------
// grid 1024 = b(4) x head(4) x rowtile(64 of 32 rows); block = 8 waves =
// wtile(2 subtiles of 16 rows) x par(4 j-parities). Depth-1 register pipeline
// on the V fragments + mask word (the only L2-latency loads).
__global__ __launch_bounds__(512) void k_attn_g(const unsigned short* __restrict__ VT,
                                                const float* __restrict__ ei_t,
                                                const float* __restrict__ ej_t,
                                                const unsigned long long* __restrict__ bits,
                                                float* __restrict__ out) {
    __shared__ float red[3][2][64][13];   // [par-1][wtile][lane][12 vals], pad 13

    const int tid = threadIdx.x;
    const int bid = blockIdx.x;
    const int rt = bid & 63;
    const int head = (bid >> 6) & 3;
    const int b = bid >> 8;
    const int wv = tid >> 6, lane = tid & 63;
    const int wtile = wv & 1, par = wv >> 1;        // par 0..3
    const int lr = lane & 15;
    const int g = lane >> 4;
    const int rowW = rt * 32 + wtile * 16;
    const int bh = b * 4 + head;

    const unsigned short* V0 = VT + (size_t)bh * 32 * 2048 + (size_t)lr * 2048;
    const unsigned short* V1 = V0 + 16 * 2048;
    const float* ejp = ej_t + (size_t)bh * 2048;
    const float eir = ei_t[(size_t)bh * 2048 + rowW + lr];
    const unsigned long long* mrow = bits + (size_t)(rowW + lr) * (N / 64);

    f32x4 acc0 = {0.f, 0.f, 0.f, 0.f};
    f32x4 acc1 = {0.f, 0.f, 0.f, 0.f};
    f32x4 accS = {0.f, 0.f, 0.f, 0.f};
    short8 onesb;
    {
        short ov = (lr == 0) ? (short)0x3F80 : (short)0;   // bf16 1.0 in col 0
#pragma unroll
        for (int e = 0; e < 8; ++e) onesb[e] = ov;
    }

    const int jstart = par * 64;   // chunks: jstart + k*256, k = 0..7

    // chunk loader: V fragments for both 32-j slices + mask word
    auto LDC = [&](int jc, unsigned long long& w,
                   short8& v00, short8& v10, short8& v01, short8& v11) {
        w = mrow[jc >> 6];
        v00 = *(const short8*)(V0 + jc + g * 8);
        v10 = *(const short8*)(V1 + jc + g * 8);
        v01 = *(const short8*)(V0 + jc + 32 + g * 8);
        v11 = *(const short8*)(V1 + jc + 32 + g * 8);
    };
    // chunk compute: scores -> bf16 P -> 3 MFMAs per 32-j slice
    auto CMP = [&](int jc, unsigned long long word,
                   short8 v00, short8 v10, short8 v01, short8 v11) {
#pragma unroll
        for (int ks = 0; ks < 2; ++ks) {
            const int joff = jc + ks * 32 + g * 8;
            float4 ea = *(const float4*)(ejp + joff);
            float4 eb = *(const float4*)(ejp + joff + 4);
            const unsigned int mb = (unsigned int)(word >> (ks * 32 + g * 8)) & 0xffu;
            float ej8[8] = {ea.x, ea.y, ea.z, ea.w, eb.x, eb.y, eb.z, eb.w};
            short8 pa;
#pragma unroll
            for (int e = 0; e < 8; ++e) {
                float s = eir + ej8[e];                     // log2-domain score
                float el = fmaxf(s, NEG * s);               // leaky (scale-commutes)
                float p = ((mb >> e) & 1u) ? __builtin_amdgcn_exp2f(el) : 0.f;
                __hip_bfloat16 pb = __float2bfloat16(p);
                pa[e] = (short)*(unsigned short*)&pb;
            }
            short8 u0 = ks ? v01 : v00;
            short8 u1 = ks ? v11 : v10;
            acc0 = __builtin_amdgcn_mfma_f32_16x16x32_bf16(pa, u0, acc0, 0, 0, 0);
            acc1 = __builtin_amdgcn_mfma_f32_16x16x32_bf16(pa, u1, acc1, 0, 0, 0);
            accS = __builtin_amdgcn_mfma_f32_16x16x32_bf16(pa, onesb, accS, 0, 0, 0);
        }
    };

    unsigned long long wA, wB;
    short8 A00, A10, A01, A11, B00, B10, B01, B11;
    int jc = jstart;
    LDC(jc, wA, A00, A10, A01, A11);
#pragma unroll 1
    for (int it = 0; it < 4; ++it) {        // 8 chunks, 2 per iteration
        int j1 = jc + 256; if (j1 >= N) j1 = jstart;
        LDC(j1, wB, B00, B10, B01, B11);
        CMP(jc, wA, A00, A10, A01, A11);
        int j2 = j1 + 256; if (j2 >= N) j2 = jstart;
        LDC(j2, wA, A00, A10, A01, A11);    // last one wraps (harmless)
        CMP(j1, wB, B00, B10, B01, B11);
        jc = j2;
    }

    // combine the 4 j-parities through LDS
    if (par != 0) {
        float* r = &red[par - 1][wtile][lane][0];
#pragma unroll
        for (int q = 0; q < 4; ++q) {
            r[q] = acc0[q]; r[4 + q] = acc1[q]; r[8 + q] = accS[q];
        }
    }
    __syncthreads();
    if (par == 0) {
#pragma unroll
        for (int p = 0; p < 3; ++p) {
            const float* r = &red[p][wtile][lane][0];
#pragma unroll
            for (int q = 0; q < 4; ++q) {
                acc0[q] += r[q]; acc1[q] += r[4 + q]; accS[q] += r[8 + q];
            }
        }
        // C/D layout (HW-verified): col = lane&15, row = 4*(lane>>4)+reg.
        // rowsum of row m sits at col 0 -> lane g*16, reg = m&3.
#pragma unroll
        for (int reg = 0; reg < 4; ++reg) {
            const float sr = __shfl(accS[reg], g * 16);
            const float inv = 1.f / sr;
            const int m = 4 * g + reg;
            float* dst = &out[(size_t)(b * N + rowW + m) * 128 + head * 32 + lr];
            dst[0]  = acc0[reg] * inv;
            dst[16] = acc1[reg] * inv;
        }
    }
}

// ================= FALLBACK: ZERO-WORKSPACE FUSED KERNEL =================
__global__ __launch_bounds__(256) void k_fused(const float* __restrict__ x,
                                               const int* __restrict__ adj,
                                               const float* __restrict__ W,
                                               const float* __restrict__ a,
                                               float* __restrict__ out) {
    __shared__ float Ws[32][129];
    __shared__ float xs[64][132];
    __shared__ float hs[64][44];
    __shared__ float ejs[64];
    __shared__ float eis[128];
    __shared__ float a1s[32], a2s[32];
    __shared__ unsigned long long mb[128];

    const int tid = threadIdx.x;
    const int bid = blockIdx.x;
    const int rt = bid & 15;
    const int head = (bid >> 4) & 3;
    const int b = bid >> 6;
    const int row0 = rt * 128;

    for (int idx = tid; idx < 32 * 128; idx += 256) {
        int d = idx >> 7, k = idx & 127;
        Ws[d][k] = W[(head * 32 + d) * 128 + k];
    }
    if (tid < 32) a1s[tid] = a[head * 64 + tid];
    else if (tid < 64) a2s[tid - 32] = a[head * 64 + tid];
    __syncthreads();

    for (int c0 = 0; c0 < 128; c0 += 64) {
        __syncthreads();
        {
            int jj = tid >> 2, k0 = (tid & 3) * 32;
            const float4* src = (const float4*)&x[(b * N + row0 + c0 + jj) * 128 + k0];
#pragma unroll
            for (int q = 0; q < 8; ++q) *(float4*)&xs[jj][k0 + q * 4] = src[q];
        }
        __syncthreads();
        {
            int jj = tid >> 2, db = (tid & 3) * 8;
#pragma unroll
            for (int dd = 0; dd < 8; ++dd) {
                float s = 0.f;
                for (int k = 0; k < 128; ++k) s += xs[jj][k] * Ws[db + dd][k];
                hs[jj][db + dd] = s;
            }
        }
        __syncthreads();
        if (tid < 64) {
            float s = 0.f;
#pragma unroll
            for (int d = 0; d < 32; ++d) s += hs[tid][d] * a1s[d];
            eis[c0 + tid] = s;
        }
    }

    const int dgrp = tid & 3, d0 = dgrp * 8;
    const int rseg = tid >> 2;
    float acc[2][8];
    float sacc[2] = {0.f, 0.f};
#pragma unroll
    for (int k = 0; k < 2; ++k)
#pragma unroll
        for (int d = 0; d < 8; ++d) acc[k][d] = 0.f;

    for (int jc = 0; jc < N; jc += 64) {
        __syncthreads();
        {
            int jj = tid >> 2, k0 = (tid & 3) * 32;
            const float4* src = (const float4*)&x[(b * N + jc + jj) * 128 + k0];
#pragma unroll
            for (int q = 0; q < 8; ++q) *(float4*)&xs[jj][k0 + q * 4] = src[q];
        }
        {
            int wv = tid >> 6, lane = tid & 63;
            for (int p = 0; p < 32; ++p) {
                int il = p * 4 + wv;
                unsigned long long m = __ballot(adj[(row0 + il) * N + jc + lane] != 0);
                if (lane == 0) mb[il] = m;
            }
        }
        __syncthreads();
        {
            int jj = tid >> 2, db = (tid & 3) * 8;
#pragma unroll
            for (int dd = 0; dd < 8; ++dd) {
                float s = 0.f;
                for (int k = 0; k < 128; ++k) s += xs[jj][k] * Ws[db + dd][k];
                hs[jj][db + dd] = s;
            }
        }
        __syncthreads();
        if (tid < 64) {
            float s = 0.f;
#pragma unroll
            for (int d = 0; d < 32; ++d) s += hs[tid][d] * a2s[d];
            ejs[tid] = s;
        }
        __syncthreads();
        for (int jj = 0; jj < 64; ++jj) {
            float ejv = ejs[jj];
            float hv[8];
#pragma unroll
            for (int d = 0; d < 8; ++d) hv[d] = hs[jj][d0 + d];
#pragma unroll
            for (int k = 0; k < 2; ++k) {
                int il = rseg * 2 + k;
                float s = eis[il] + ejv;
                float el = s > 0.f ? s : NEG * s;
                float p = ((mb[il] >> jj) & 1ull) ? __expf(el) : 0.f;
                sacc[k] += p;
#pragma unroll
                for (int d = 0; d < 8; ++d) acc[k][d] += p * hv[d];
            }
        }
    }
#pragma unroll
    for (int k = 0; k < 2; ++k) {
        int il = rseg * 2 + k;
        float inv = 1.f / sacc[k];
        float* dst = &out[(b * N + row0 + il) * 128 + head * 32 + d0];
#pragma unroll
        for (int d = 0; d < 8; ++d) dst[d] = acc[k][d] * inv;
    }
}

extern "C" void kernel_launch(void* const* d_in, const int* in_sizes, int n_in,
                              void* d_out, int out_size, void* d_ws, size_t ws_size,
                              hipStream_t stream) {
    // Identify inputs by element count (all unique) — order-proof.
    const float* x = nullptr; const int* adj = nullptr;
    const float* W = nullptr; const float* a = nullptr;
    for (int i = 0; i < n_in; ++i) {
        switch (in_sizes[i]) {
            case B * N * DIN:  x   = (const float*)d_in[i]; break;  // 1048576
            case N * N:        adj = (const int*)d_in[i];   break;  // 4194304
            case H * HD * DIN: W   = (const float*)d_in[i]; break;  // 16384
            case H * 2 * HD:   a   = (const float*)d_in[i]; break;  // 256
        }
    }
    float* out = (float*)d_out;   // reference output dtype is float32

    // ws: VT bf16 2MB | ei_t 128KB | ej_t 128KB | bits 512KB  = 2.75 MB
    const size_t szVT = (size_t)B * H * HD * N * 2;
    const size_t szE  = (size_t)B * H * N * 4;
    const size_t szBits = (size_t)N * (N / 64) * 8;
    const size_t need = szVT + 2 * szE + szBits;

    if (ws_size >= need) {
        char* ws = (char*)d_ws;
        unsigned short* VT = (unsigned short*)ws;
        float* ei_t = (float*)(ws + szVT);
        float* ej_t = (float*)(ws + szVT + szE);
        unsigned long long* bits = (unsigned long long*)(ws + szVT + 2 * szE);

        k_gemm<<<512, 256, 0, stream>>>(x, W, a, VT, ei_t, ej_t);
        k_pack<<<(N * N) / 256, 256, 0, stream>>>(adj, bits);
        k_attn_g<<<1024, 512, 0, stream>>>(VT, ei_t, ej_t, bits, out);
    } else {
        k_fused<<<256, 256, 0, stream>>>(x, adj, W, a, out);
    }
}

// Round 9
// 111.694 us; speedup vs baseline: 2.5850x; 1.1650x over previous
//
#include <hip/hip_runtime.h>
#include <hip/hip_bf16.h>
#include <stdint.h>

#define B 4
#define N 2048
#define DIN 128
#define H 4
#define HD 32
#define NEG 0.2f
#define LOG2E 1.4426950408889634f
#define WINJ 512

typedef __attribute__((ext_vector_type(8))) short short8;
typedef __attribute__((ext_vector_type(4))) float f32x4;

// ---------- Kernel 1: prep = gemm(+VT pre-swizzled, ei/ej) ++ adjacency pack ----------
// blocks [0,512): gemm, 16 rows each. blocks [512,16896): pack.
__global__ __launch_bounds__(256) void k_prep(const float* __restrict__ x,
                                              const float* __restrict__ W,
                                              const float* __restrict__ a,
                                              const int* __restrict__ adj,
                                              unsigned short* __restrict__ VT,
                                              float* __restrict__ ei_t,
                                              float* __restrict__ ej_t,
                                              unsigned long long* __restrict__ bits) {
    __shared__ float Wt0[64][64];
    __shared__ float Wt1[64][64];
    __shared__ float xT[64][20];

    const int tid = threadIdx.x;
    if (blockIdx.x >= 512) {            // ---- pack part ----
        int t = (blockIdx.x - 512) * 256 + tid;
        int v = adj[t];
        unsigned long long m = __ballot(v != 0);
        if ((tid & 63) == 0) bits[t >> 6] = m;
        return;
    }

    // ---- gemm part ----
    const int lane = tid & 63;
    const int r0 = (tid >> 6) * 4;
    const int c2 = lane;
    const int rowBase = blockIdx.x * 16;
    float acc[4][2];
#pragma unroll
    for (int i = 0; i < 4; ++i) { acc[i][0] = 0.f; acc[i][1] = 0.f; }

    for (int kh = 0; kh < 2; ++kh) {
        __syncthreads();
        {   // stage W half, even/odd col planes
            const int c = tid & 127;
            const int qb = (tid >> 7) * 8;
            const int ci = c >> 1, pl = c & 1;
            const float4* W4 = (const float4*)W;
#pragma unroll
            for (int q = 0; q < 8; ++q) {
                float4 v = W4[c * 32 + kh * 16 + qb + q];
                int kk = (qb + q) * 4;
                if (pl == 0) {
                    Wt0[kk + 0][ci] = v.x; Wt0[kk + 1][ci] = v.y;
                    Wt0[kk + 2][ci] = v.z; Wt0[kk + 3][ci] = v.w;
                } else {
                    Wt1[kk + 0][ci] = v.x; Wt1[kk + 1][ci] = v.y;
                    Wt1[kk + 2][ci] = v.z; Wt1[kk + 3][ci] = v.w;
                }
            }
        }
        {   // stage x
            const int rl = tid >> 4;
            const int q = tid & 15;
            float4 v = ((const float4*)x)[(rowBase + rl) * 32 + kh * 16 + q];
            int kk = q * 4;
            xT[kk + 0][rl] = v.x; xT[kk + 1][rl] = v.y;
            xT[kk + 2][rl] = v.z; xT[kk + 3][rl] = v.w;
        }
        __syncthreads();
#pragma unroll 8
        for (int kk = 0; kk < 64; ++kk) {
            float w0 = Wt0[kk][c2];
            float w1 = Wt1[kk][c2];
#pragma unroll
            for (int i = 0; i < 4; ++i) {
                float xv = xT[kk][r0 + i];
                acc[i][0] += xv * w0;
                acc[i][1] += xv * w1;
            }
        }
    }

    const int c0 = 2 * c2;
    const int head = c0 >> 5, d0 = c0 & 31;
    const int b = rowBase >> 11;
    const int n0 = (rowBase & 2047) + r0;
    const int bh = b * 4 + head;

    {   // V^T bf16, PRE-SWIZZLED: granule (16B) index ^= (d&7) within 512-j window
        ushort4 p0, p1;
        unsigned short* q0 = (unsigned short*)&p0;
        unsigned short* q1 = (unsigned short*)&p1;
#pragma unroll
        for (int i = 0; i < 4; ++i) {
            __hip_bfloat16 h0 = __float2bfloat16(acc[i][0]);
            __hip_bfloat16 h1 = __float2bfloat16(acc[i][1]);
            q0[i] = *(unsigned short*)&h0;
            q1[i] = *(unsigned short*)&h1;
        }
        const int wdw = n0 >> 9;
        const int gw  = (n0 >> 3) & 63;
        const int off = n0 & 7;                // 0 or 4 (8B-aligned half-granule)
        const int gs0 = gw ^ (d0 & 7);
        const int gs1 = gw ^ ((d0 + 1) & 7);
        *(ushort4*)&VT[((size_t)bh * 32 + d0) * 2048 + wdw * WINJ + gs0 * 8 + off] = p0;
        *(ushort4*)&VT[((size_t)bh * 32 + d0 + 1) * 2048 + wdw * WINJ + gs1 * 8 + off] = p1;
    }
    {   // ei/ej (log2e-scaled), f32 precision
        float a10 = a[head * 64 + d0],      a11 = a[head * 64 + d0 + 1];
        float a20 = a[head * 64 + 32 + d0], a21 = a[head * 64 + 32 + d0 + 1];
#pragma unroll
        for (int i = 0; i < 4; ++i) {
            float pi = acc[i][0] * a10 + acc[i][1] * a11;
            float pj = acc[i][0] * a20 + acc[i][1] * a21;
#pragma unroll
            for (int off = 1; off < 16; off <<= 1) {
                pi += __shfl_xor(pi, off);
                pj += __shfl_xor(pj, off);
            }
            if ((lane & 15) == 0) {
                ei_t[(size_t)bh * 2048 + n0 + i] = pi * LOG2E;
                ej_t[(size_t)bh * 2048 + n0 + i] = pj * LOG2E;
            }
        }
    }
}

// ---------- Kernel 2: MFMA attention, V in LDS (swizzled), windowed dbuf ----------
// grid 256 = b(4) x head(4) x rowtile(16 of 128 rows); block = 8 waves x 16 rows.
// Each wave owns its rows for ALL j (no parity combine). V window 512 j staged
// to LDS each iter (reg-staged, issue-early/write-late); 1 barrier per window.
__global__ __launch_bounds__(512) void k_attn_l(const unsigned short* __restrict__ VT,
                                                const float* __restrict__ ei_t,
                                                const float* __restrict__ ej_t,
                                                const unsigned long long* __restrict__ bits,
                                                float* __restrict__ out) {
    __shared__ unsigned short Vs[2][32 * WINJ];   // 2 x 32KB, swizzled granules
    __shared__ float ejs[2][WINJ];                // 2 x 2KB

    const int tid = threadIdx.x;
    const int bid = blockIdx.x;
    const int rt = bid & 15;
    const int head = (bid >> 4) & 3;
    const int b = bid >> 6;
    const int wv = tid >> 6, lane = tid & 63;
    const int lr = lane & 15;
    const int g = lane >> 4;
    const int rowW = rt * 128 + wv * 16;
    const int bh = b * 4 + head;

    const unsigned short* VTb = VT + (size_t)bh * 32 * 2048;
    const float* ejg = ej_t + (size_t)bh * 2048;
    const float eir = ei_t[(size_t)bh * 2048 + rowW + lr];
    const unsigned long long* mrow = bits + (size_t)(rowW + lr) * (N / 64);

    f32x4 acc0 = {0.f, 0.f, 0.f, 0.f};
    f32x4 acc1 = {0.f, 0.f, 0.f, 0.f};
    f32x4 accS = {0.f, 0.f, 0.f, 0.f};
    short8 onesb;
    {
        short ov = (lr == 0) ? (short)0x3F80 : (short)0;
#pragma unroll
        for (int e = 0; e < 8; ++e) onesb[e] = ov;
    }

    // ---- prologue: stage window 0 ----
    {
#pragma unroll
        for (int i = 0; i < 4; ++i) {
            int L = i * 512 + tid, d = L >> 6, gr = L & 63;
            float4 v = *(const float4*)&VTb[(size_t)d * 2048 + gr * 8];
            *(float4*)&Vs[0][(size_t)L * 8] = v;
        }
        if (tid < 128) {
            float4 e = *(const float4*)&ejg[tid * 4];
            *(float4*)&ejs[0][tid * 4] = e;
        }
    }
    __syncthreads();

    for (int w = 0; w < 4; ++w) {
        const int buf = w & 1;
        float4 vr0, vr1, vr2, vr3, er;
        const bool pf = (w < 3);
        if (pf) {   // issue next-window loads EARLY (hide under compute)
            const unsigned short* src = VTb + (w + 1) * WINJ;
            int L0 = tid,        d0_ = L0 >> 6, g0_ = L0 & 63;
            int L1 = 512 + tid,  d1_ = L1 >> 6, g1_ = L1 & 63;
            int L2 = 1024 + tid, d2_ = L2 >> 6, g2_ = L2 & 63;
            int L3 = 1536 + tid, d3_ = L3 >> 6, g3_ = L3 & 63;
            vr0 = *(const float4*)&src[(size_t)d0_ * 2048 + g0_ * 8];
            vr1 = *(const float4*)&src[(size_t)d1_ * 2048 + g1_ * 8];
            vr2 = *(const float4*)&src[(size_t)d2_ * 2048 + g2_ * 8];
            vr3 = *(const float4*)&src[(size_t)d3_ * 2048 + g3_ * 8];
            if (tid < 128) er = *(const float4*)&ejg[(w + 1) * WINJ + tid * 4];
        }
        __builtin_amdgcn_sched_barrier(0);   // pin load issue before compute

        const unsigned short* Vb = &Vs[buf][0];
        const float* ejb = &ejs[buf][0];
#pragma unroll 4
        for (int jl = 0; jl < WINJ; jl += 64) {
            const unsigned long long word = mrow[(w * WINJ + jl) >> 6];
#pragma unroll
            for (int ks = 0; ks < 2; ++ks) {
                const int G = (jl >> 3) + ks * 4 + g;
                const int gs = (G ^ (lr & 7)) * 8;
                short8 b0 = *(const short8*)&Vb[lr * WINJ + gs];
                short8 b1 = *(const short8*)&Vb[(16 + lr) * WINJ + gs];
                const int f = jl + ks * 32 + g * 8;
                float4 ea = *(const float4*)&ejb[f];
                float4 eb = *(const float4*)&ejb[f + 4];
                const unsigned int mb =
                    (unsigned int)(word >> (ks * 32 + g * 8)) & 0xffu;
                float ej8[8] = {ea.x, ea.y, ea.z, ea.w, eb.x, eb.y, eb.z, eb.w};
                short8 pa;
#pragma unroll
                for (int e = 0; e < 8; ++e) {
                    float s = eir + ej8[e];
                    float el = fmaxf(s, NEG * s);
                    float p = ((mb >> e) & 1u) ? __builtin_amdgcn_exp2f(el) : 0.f;
                    __hip_bfloat16 pb = __float2bfloat16(p);
                    pa[e] = (short)*(unsigned short*)&pb;
                }
                acc0 = __builtin_amdgcn_mfma_f32_16x16x32_bf16(pa, b0, acc0, 0, 0, 0);
                acc1 = __builtin_amdgcn_mfma_f32_16x16x32_bf16(pa, b1, acc1, 0, 0, 0);
                accS = __builtin_amdgcn_mfma_f32_16x16x32_bf16(pa, onesb, accS, 0, 0, 0);
            }
        }

        if (pf) {   // write-late into the other buffer
            const int nbuf = buf ^ 1;
            *(float4*)&Vs[nbuf][(size_t)tid * 8]          = vr0;
            *(float4*)&Vs[nbuf][(size_t)(512 + tid) * 8]  = vr1;
            *(float4*)&Vs[nbuf][(size_t)(1024 + tid) * 8] = vr2;
            *(float4*)&Vs[nbuf][(size_t)(1536 + tid) * 8] = vr3;
            if (tid < 128) *(float4*)&ejs[nbuf][tid * 4] = er;
        }
        __syncthreads();
    }

    // ---- epilogue: rowsum from ones-MFMA col0, normalize, store ----
    // C/D layout (HW-verified): col = lane&15, row = 4*(lane>>4)+reg.
#pragma unroll
    for (int reg = 0; reg < 4; ++reg) {
        const float sr = __shfl(accS[reg], g * 16);
        const float inv = 1.f / sr;
        const int m = 4 * g + reg;
        float* dst = &out[(size_t)(b * N + rowW + m) * 128 + head * 32 + lr];
        dst[0]  = acc0[reg] * inv;
        dst[16] = acc1[reg] * inv;
    }
}

// ================= FALLBACK: ZERO-WORKSPACE FUSED KERNEL =================
__global__ __launch_bounds__(256) void k_fused(const float* __restrict__ x,
                                               const int* __restrict__ adj,
                                               const float* __restrict__ W,
                                               const float* __restrict__ a,
                                               float* __restrict__ out) {
    __shared__ float Ws[32][129];
    __shared__ float xs[64][132];
    __shared__ float hs[64][44];
    __shared__ float ejs[64];
    __shared__ float eis[128];
    __shared__ float a1s[32], a2s[32];
    __shared__ unsigned long long mb[128];

    const int tid = threadIdx.x;
    const int bid = blockIdx.x;
    const int rt = bid & 15;
    const int head = (bid >> 4) & 3;
    const int b = bid >> 6;
    const int row0 = rt * 128;

    for (int idx = tid; idx < 32 * 128; idx += 256) {
        int d = idx >> 7, k = idx & 127;
        Ws[d][k] = W[(head * 32 + d) * 128 + k];
    }
    if (tid < 32) a1s[tid] = a[head * 64 + tid];
    else if (tid < 64) a2s[tid - 32] = a[head * 64 + tid];
    __syncthreads();

    for (int c0 = 0; c0 < 128; c0 += 64) {
        __syncthreads();
        {
            int jj = tid >> 2, k0 = (tid & 3) * 32;
            const float4* src = (const float4*)&x[(b * N + row0 + c0 + jj) * 128 + k0];
#pragma unroll
            for (int q = 0; q < 8; ++q) *(float4*)&xs[jj][k0 + q * 4] = src[q];
        }
        __syncthreads();
        {
            int jj = tid >> 2, db = (tid & 3) * 8;
#pragma unroll
            for (int dd = 0; dd < 8; ++dd) {
                float s = 0.f;
                for (int k = 0; k < 128; ++k) s += xs[jj][k] * Ws[db + dd][k];
                hs[jj][db + dd] = s;
            }
        }
        __syncthreads();
        if (tid < 64) {
            float s = 0.f;
#pragma unroll
            for (int d = 0; d < 32; ++d) s += hs[tid][d] * a1s[d];
            eis[c0 + tid] = s;
        }
    }

    const int dgrp = tid & 3, d0 = dgrp * 8;
    const int rseg = tid >> 2;
    float acc[2][8];
    float sacc[2] = {0.f, 0.f};
#pragma unroll
    for (int k = 0; k < 2; ++k)
#pragma unroll
        for (int d = 0; d < 8; ++d) acc[k][d] = 0.f;

    for (int jc = 0; jc < N; jc += 64) {
        __syncthreads();
        {
            int jj = tid >> 2, k0 = (tid & 3) * 32;
            const float4* src = (const float4*)&x[(b * N + jc + jj) * 128 + k0];
#pragma unroll
            for (int q = 0; q < 8; ++q) *(float4*)&xs[jj][k0 + q * 4] = src[q];
        }
        {
            int wv = tid >> 6, lane = tid & 63;
            for (int p = 0; p < 32; ++p) {
                int il = p * 4 + wv;
                unsigned long long m = __ballot(adj[(row0 + il) * N + jc + lane] != 0);
                if (lane == 0) mb[il] = m;
            }
        }
        __syncthreads();
        {
            int jj = tid >> 2, db = (tid & 3) * 8;
#pragma unroll
            for (int dd = 0; dd < 8; ++dd) {
                float s = 0.f;
                for (int k = 0; k < 128; ++k) s += xs[jj][k] * Ws[db + dd][k];
                hs[jj][db + dd] = s;
            }
        }
        __syncthreads();
        if (tid < 64) {
            float s = 0.f;
#pragma unroll
            for (int d = 0; d < 32; ++d) s += hs[tid][d] * a2s[d];
            ejs[tid] = s;
        }
        __syncthreads();
        for (int jj = 0; jj < 64; ++jj) {
            float ejv = ejs[jj];
            float hv[8];
#pragma unroll
            for (int d = 0; d < 8; ++d) hv[d] = hs[jj][d0 + d];
#pragma unroll
            for (int k = 0; k < 2; ++k) {
                int il = rseg * 2 + k;
                float s = eis[il] + ejv;
                float el = s > 0.f ? s : NEG * s;
                float p = ((mb[il] >> jj) & 1ull) ? __expf(el) : 0.f;
                sacc[k] += p;
#pragma unroll
                for (int d = 0; d < 8; ++d) acc[k][d] += p * hv[d];
            }
        }
    }
#pragma unroll
    for (int k = 0; k < 2; ++k) {
        int il = rseg * 2 + k;
        float inv = 1.f / sacc[k];
        float* dst = &out[(b * N + row0 + il) * 128 + head * 32 + d0];
#pragma unroll
        for (int d = 0; d < 8; ++d) dst[d] = acc[k][d] * inv;
    }
}

extern "C" void kernel_launch(void* const* d_in, const int* in_sizes, int n_in,
                              void* d_out, int out_size, void* d_ws, size_t ws_size,
                              hipStream_t stream) {
    // Identify inputs by element count (all unique) — order-proof.
    const float* x = nullptr; const int* adj = nullptr;
    const float* W = nullptr; const float* a = nullptr;
    for (int i = 0; i < n_in; ++i) {
        switch (in_sizes[i]) {
            case B * N * DIN:  x   = (const float*)d_in[i]; break;  // 1048576
            case N * N:        adj = (const int*)d_in[i];   break;  // 4194304
            case H * HD * DIN: W   = (const float*)d_in[i]; break;  // 16384
            case H * 2 * HD:   a   = (const float*)d_in[i]; break;  // 256
        }
    }
    float* out = (float*)d_out;   // reference output dtype is float32

    // ws: VT bf16 2MB | ei_t 128KB | ej_t 128KB | bits 512KB  = 2.75 MB
    const size_t szVT = (size_t)B * H * HD * N * 2;
    const size_t szE  = (size_t)B * H * N * 4;
    const size_t szBits = (size_t)N * (N / 64) * 8;
    const size_t need = szVT + 2 * szE + szBits;

    if (ws_size >= need) {
        char* ws = (char*)d_ws;
        unsigned short* VT = (unsigned short*)ws;
        float* ei_t = (float*)(ws + szVT);
        float* ej_t = (float*)(ws + szVT + szE);
        unsigned long long* bits = (unsigned long long*)(ws + szVT + 2 * szE);

        k_prep<<<512 + (N * N) / 256, 256, 0, stream>>>(x, W, a, adj, VT, ei_t, ej_t, bits);
        k_attn_l<<<256, 512, 0, stream>>>(VT, ei_t, ej_t, bits, out);
    } else {
        k_fused<<<256, 256, 0, stream>>>(x, adj, W, a, out);
    }
}